// Round 11
// baseline (139.843 us; speedup 1.0000x reference)
//
#include <hip/hip_runtime.h>
#include <hip/hip_bf16.h>

#define DIM 128
#define NPB 512                 // nodes per bucket (pow2, shift 9)
#define NPB_SHIFT 9
// NN < 2^17 (=131072) required by the 17-bit src/dst packing; harness uses 100000.

#define FROWS 64      // finish: M-tile rows per block
#define FPAD 136      // bf16 row stride in LDS: 272B -> 2-way bank alias on b128 (free)

typedef __attribute__((ext_vector_type(8))) short bf16x8;
typedef __attribute__((ext_vector_type(8))) unsigned short u16x8;
typedef __attribute__((ext_vector_type(4))) float f32x4;

__device__ __forceinline__ short f2bf(float f) {
    union { __hip_bfloat16 h; short s; } u;
    u.h = __float2bfloat16(f);   // round-to-nearest-even
    return u.s;
}
__device__ __forceinline__ float bf2f(unsigned short s) {
    union { unsigned int u; float f; } c;
    c.u = ((unsigned int)s) << 16;
    return c.f;
}

__device__ __forceinline__ int load_dst(const void* eidx, int flag64, int E, int e) {
    return flag64 ? (int)((const long long*)eidx)[E + e] : ((const int*)eidx)[E + e];
}
__device__ __forceinline__ int load_src(const void* eidx, int flag64, int E, int e) {
    return flag64 ? (int)((const long long*)eidx)[e] : ((const int*)eidx)[e];
}

// ---------------------------------------------------------------------------
// Init (1 block): zero bucket counters + detect int64/int32 edge index
// (values < 2^17 => int64 high words of first 128 entries all zero).
// Must complete before prep's hist atomics (stream order guarantees it).
// ---------------------------------------------------------------------------
__global__ __launch_bounds__(256) void init_kernel(
        int* __restrict__ gcnt, const unsigned int* __restrict__ e,
        int* __restrict__ flags) {
    gcnt[threadIdx.x] = 0;
    if (threadIdx.x == 0) {
        int ok64 = 1;
        for (int t = 0; t < 128; ++t) {
            if (e[2 * t + 1] != 0u) { ok64 = 0; break; }
        }
        flags[0] = ok64;
    }
}

// ---------------------------------------------------------------------------
// Prep (fused): cvt x f32 -> xb bf16 AND bucket histogram (LDS hist per
// block -> one global atomic per (block,bucket)).
// ---------------------------------------------------------------------------
__global__ __launch_bounds__(256) void prep_kernel(
        const float* __restrict__ x, unsigned short* __restrict__ xb, int n8,
        const void* __restrict__ eidx, int* __restrict__ gcnt,
        const int* __restrict__ flags, int E, int NB) {
    __shared__ int bcnt[256];
    const int tid = threadIdx.x;
    bcnt[tid] = 0;
    __syncthreads();

    const int stride = gridDim.x * blockDim.x;
    const int t0 = blockIdx.x * blockDim.x + tid;
    const int f = flags[0];

    for (int e = t0; e < E; e += stride)
        atomicAdd(&bcnt[load_dst(eidx, f, E, e) >> NPB_SHIFT], 1);

    for (int t = t0; t < n8; t += stride) {
        const float4* pp = (const float4*)(x + (size_t)t * 8);
        float4 a = pp[0], b = pp[1];
        u16x8 o;
        o[0] = (unsigned short)f2bf(a.x); o[1] = (unsigned short)f2bf(a.y);
        o[2] = (unsigned short)f2bf(a.z); o[3] = (unsigned short)f2bf(a.w);
        o[4] = (unsigned short)f2bf(b.x); o[5] = (unsigned short)f2bf(b.y);
        o[6] = (unsigned short)f2bf(b.z); o[7] = (unsigned short)f2bf(b.w);
        *(u16x8*)(xb + (size_t)t * 8) = o;
    }

    __syncthreads();
    if (tid < NB && bcnt[tid] > 0) atomicAdd(&gcnt[tid], bcnt[tid]);
}

// ---------------------------------------------------------------------------
// Bucket scan (single block): gstart = exclusive scan of gcnt; gcursor = copy;
// gstart[NB] = E.
// ---------------------------------------------------------------------------
__global__ __launch_bounds__(256) void scanb_kernel(
        const int* __restrict__ gcnt, int* __restrict__ gstart,
        int* __restrict__ gcursor, int NB, int E) {
    __shared__ int s[256];
    const int tid = threadIdx.x;
    int val = (tid < NB) ? gcnt[tid] : 0;
    s[tid] = val;
    __syncthreads();
    for (int off = 1; off < 256; off <<= 1) {
        int t = (tid >= off) ? s[tid - off] : 0;
        __syncthreads();
        s[tid] += t;
        __syncthreads();
    }
    int excl = s[tid] - val;
    if (tid < NB) { gstart[tid] = excl; gcursor[tid] = excl; }
    if (tid == NB) gstart[NB] = E;   // NB < 256 guaranteed (NN < 2^17)
}

// ---------------------------------------------------------------------------
// A1 partition: 2048 edges/block (313 blocks). Stage edges in LDS grouped by
// bucket (pk = w32[57:26] | dst_local[25:17] | src[16:0]), reserve per-bucket
// runs (one atomic per block,bucket), write runs contiguously.
// ---------------------------------------------------------------------------
#define A1_EPT 8
#define A1_EPB (256 * A1_EPT)
__global__ __launch_bounds__(256) void part_kernel(
        const void* __restrict__ eidx, const float* __restrict__ ew,
        int* __restrict__ gcursor, unsigned long long* __restrict__ srcw_tmp,
        const int* __restrict__ flags, int E) {
    __shared__ unsigned long long stage[A1_EPB];   // 16 KB
    __shared__ unsigned char sbid[A1_EPB];         //  2 KB
    __shared__ int bcnt[256], bscan[256], bcur[256], brun[256];
    const int tid = threadIdx.x;
    const int base = blockIdx.x * A1_EPB;
    const int f = flags[0];

    bcnt[tid] = 0;
    __syncthreads();

    unsigned long long pk[A1_EPT];
    unsigned char bid[A1_EPT];
    #pragma unroll
    for (int i = 0; i < A1_EPT; ++i) {
        int e = base + tid + i * 256;
        bid[i] = 0xFF;
        if (e < E) {
            int src = load_src(eidx, f, E, e);
            int dst = load_dst(eidx, f, E, e);
            unsigned int w = __float_as_uint(ew[e]);
            int b = dst >> NPB_SHIFT;
            pk[i] = ((unsigned long long)w << 26)
                  | ((unsigned long long)(dst & (NPB - 1)) << 17)
                  | (unsigned long long)(unsigned)src;
            bid[i] = (unsigned char)b;
            atomicAdd(&bcnt[b], 1);
        }
    }
    __syncthreads();

    // exclusive scan of bcnt (Hillis-Steele on 256)
    int val = bcnt[tid];
    bscan[tid] = val;
    __syncthreads();
    for (int off = 1; off < 256; off <<= 1) {
        int t = (tid >= off) ? bscan[tid - off] : 0;
        __syncthreads();
        bscan[tid] += t;
        __syncthreads();
    }
    int excl = bscan[tid] - val;
    __syncthreads();
    bscan[tid] = excl;        // now exclusive
    bcur[tid] = excl;
    __syncthreads();

    // rank + stage (bucket-grouped)
    #pragma unroll
    for (int i = 0; i < A1_EPT; ++i) {
        if (bid[i] != 0xFF) {
            int slot = atomicAdd(&bcur[bid[i]], 1);
            stage[slot] = pk[i];
            sbid[slot] = bid[i];
        }
    }
    // reserve global runs
    if (bcnt[tid] > 0) brun[tid] = atomicAdd(&gcursor[tid], bcnt[tid]);
    __syncthreads();

    int tot = (base + A1_EPB <= E) ? A1_EPB : (E - base);
    for (int s = tid; s < tot; s += 256) {
        int b = sbid[s];
        srcw_tmp[brun[b] + (s - bscan[b])] = stage[s];
    }
}

// ---------------------------------------------------------------------------
// A2 bucket-local sort (512 threads/block, 1 block/bucket): count per node
// (LDS), 512-wide scan, write node rowstart (coalesced), place final
// (w<<32|src) payloads. All payload writes land in the bucket's contiguous
// slot region from ONE block -> lines fill in L2 -> ~1x write amp.
// ---------------------------------------------------------------------------
__global__ __launch_bounds__(512) void sort_kernel(
        const unsigned long long* __restrict__ srcw_tmp,
        const int* __restrict__ gstart, unsigned long long* __restrict__ srcw,
        int* __restrict__ rowstart, int nn) {
    __shared__ int cnt[NPB], cur[NPB], s[NPB];
    const int tid = threadIdx.x;
    const int b = blockIdx.x;
    const int node0 = b << NPB_SHIFT;
    const int e0 = gstart[b], e1 = gstart[b + 1];

    cnt[tid] = 0;
    __syncthreads();
    for (int e = e0 + tid; e < e1; e += 512)
        atomicAdd(&cnt[(int)((srcw_tmp[e] >> 17) & (NPB - 1))], 1);
    __syncthreads();

    // exclusive scan over 512 (Hillis-Steele)
    int val = cnt[tid];
    s[tid] = val;
    __syncthreads();
    for (int off = 1; off < 512; off <<= 1) {
        int t = (tid >= off) ? s[tid - off] : 0;
        __syncthreads();
        s[tid] += t;
        __syncthreads();
    }
    int excl = s[tid] - val;
    cur[tid] = excl;
    __syncthreads();

    // node-level rowstart (coalesced, one per thread)
    int nbn = nn - node0; if (nbn > NPB) nbn = NPB;
    if (tid < nbn) rowstart[node0 + tid] = e0 + excl;

    // place payloads
    for (int e = e0 + tid; e < e1; e += 512) {
        unsigned long long pk = srcw_tmp[e];
        int dl = (int)((pk >> 17) & (NPB - 1));
        int pos = e0 + atomicAdd(&cur[dl], 1);
        srcw[pos] = ((pk >> 26) << 32) | (pk & 0x1FFFFULL);
    }
}

// ---------------------------------------------------------------------------
// Gather: 4 nodes per wave (16 lanes per node, lane owns 8 dims = 16B bf16).
// Unified contiguous segment per node; 4-edge unroll -> up to 16 row-fetches
// in flight per wave. No atomics.
// ---------------------------------------------------------------------------
__global__ __launch_bounds__(256) void gather_kernel(
        const unsigned short* __restrict__ xb, const uint2* __restrict__ srcw,
        const int* __restrict__ rowstart, unsigned short* __restrict__ aggb,
        int nn, int E) {
    int g = (blockIdx.x * blockDim.x + threadIdx.x) >> 4;   // node
    int sub16 = threadIdx.x & 15;                           // owns dims [8*sub16, +8)
    if (g >= nn) return;
    int n0 = rowstart[g];
    int n1 = (g + 1 < nn) ? rowstart[g + 1] : E;
    float acc[8] = {0.f, 0.f, 0.f, 0.f, 0.f, 0.f, 0.f, 0.f};
    int e = n0;
    for (; e + 4 <= n1; e += 4) {
        uint2 sw0 = srcw[e];
        uint2 sw1 = srcw[e + 1];
        uint2 sw2 = srcw[e + 2];
        uint2 sw3 = srcw[e + 3];
        u16x8 x0 = *(const u16x8*)(xb + (size_t)sw0.x * DIM + sub16 * 8);
        u16x8 x1 = *(const u16x8*)(xb + (size_t)sw1.x * DIM + sub16 * 8);
        u16x8 x2 = *(const u16x8*)(xb + (size_t)sw2.x * DIM + sub16 * 8);
        u16x8 x3 = *(const u16x8*)(xb + (size_t)sw3.x * DIM + sub16 * 8);
        float w0 = __uint_as_float(sw0.y);
        float w1 = __uint_as_float(sw1.y);
        float w2 = __uint_as_float(sw2.y);
        float w3 = __uint_as_float(sw3.y);
        #pragma unroll
        for (int j = 0; j < 8; ++j) {
            acc[j] = fmaf(bf2f(x0[j]), w0, acc[j]);
            acc[j] = fmaf(bf2f(x1[j]), w1, acc[j]);
            acc[j] = fmaf(bf2f(x2[j]), w2, acc[j]);
            acc[j] = fmaf(bf2f(x3[j]), w3, acc[j]);
        }
    }
    for (; e < n1; ++e) {
        uint2 sw = srcw[e];
        u16x8 xr = *(const u16x8*)(xb + (size_t)sw.x * DIM + sub16 * 8);
        float w = __uint_as_float(sw.y);
        #pragma unroll
        for (int j = 0; j < 8; ++j) acc[j] = fmaf(bf2f(xr[j]), w, acc[j]);
    }
    float inv = 1.0f / fmaxf((float)(n1 - n0), 1.0f);
    u16x8 o;
    #pragma unroll
    for (int j = 0; j < 8; ++j) o[j] = (unsigned short)f2bf(acc[j] * inv);
    *(u16x8*)(aggb + (size_t)g * DIM + sub16 * 8) = o;
}

// ---------------------------------------------------------------------------
// MFMA finish: out = xb + alpha*(aggb @ W^T + b). aggb, xb bf16 in ws; out
// f32 in d_out. 512 threads = 8 waves; 64-row M-tile; wave w owns output
// cols [16w,16w+16). C/D map: col=lane&15, row=(lane>>4)*4+reg  [verified,
// learn_hip m89/m91]. Residual from bf16 xb: +<=0.016 abs err, OK.
// ---------------------------------------------------------------------------
__global__ __launch_bounds__(512) void finish_kernel(
        const unsigned short* __restrict__ aggb, float* __restrict__ out,
        const unsigned short* __restrict__ xb, const float* __restrict__ W,
        const float* __restrict__ bias, const float* __restrict__ alphaP, int nn) {
    __shared__ alignas(16) unsigned short A_lds[FROWS * FPAD];   // 17408 B
    const int tid  = threadIdx.x;
    const int wv   = tid >> 6;          // wave 0..7
    const int lane = tid & 63;
    const int half = lane >> 4;         // 0..3 (K-group / row-group)
    const int l16  = lane & 15;         // M-row for A, N-col for B and C/D
    const int b0   = blockIdx.x * FROWS;
    const float alpha = alphaP[0];

    // ---- B-frags: W[jcol][kt*32 + half*8 .. +8] as bf16, loaded once ----
    const int jcol = wv * 16 + l16;
    bf16x8 bfrag[4];
    #pragma unroll
    for (int kt = 0; kt < 4; ++kt) {
        const float4* w4 = (const float4*)(W + (size_t)jcol * DIM + kt * 32 + half * 8);
        float4 lo = w4[0], hi = w4[1];
        bf16x8 b;
        b[0] = f2bf(lo.x); b[1] = f2bf(lo.y); b[2] = f2bf(lo.z); b[3] = f2bf(lo.w);
        b[4] = f2bf(hi.x); b[5] = f2bf(hi.y); b[6] = f2bf(hi.z); b[7] = f2bf(hi.w);
        bfrag[kt] = b;
    }
    const float bias_j = bias[jcol];

    // ---- stage 64 bf16 agg rows -> LDS: 1024 chunks of 16B, 2 iters ----
    #pragma unroll
    for (int it = 0; it < 2; ++it) {
        int p = it * 512 + tid;          // 0..1023
        int row = p >> 4;                // 0..63
        int c8 = p & 15;                 // 16B chunk within row
        int node = b0 + row;
        u16x8 v = {0, 0, 0, 0, 0, 0, 0, 0};
        if (node < nn) v = *(const u16x8*)(aggb + (size_t)node * DIM + c8 * 8);
        *(u16x8*)&A_lds[row * FPAD + c8 * 8] = v;
    }
    __syncthreads();

    // ---- 4 sub-tiles of 16 rows: MFMA + fused epilogue ----
    #pragma unroll
    for (int mt = 0; mt < 4; ++mt) {
        f32x4 acc = {0.f, 0.f, 0.f, 0.f};
        #pragma unroll
        for (int kt = 0; kt < 4; ++kt) {
            const bf16x8 a = *(const bf16x8*)&A_lds[(mt * 16 + l16) * FPAD + kt * 32 + half * 8];
            acc = __builtin_amdgcn_mfma_f32_16x16x32_bf16(a, bfrag[kt], acc, 0, 0, 0);
        }
        #pragma unroll
        for (int r = 0; r < 4; ++r) {
            int grow = b0 + mt * 16 + half * 4 + r;
            if (grow < nn) {
                size_t idx = (size_t)grow * DIM + jcol;
                out[idx] = bf2f(xb[idx]) + alpha * (acc[r] + bias_j);
            }
        }
    }
}

extern "C" void kernel_launch(void* const* d_in, const int* in_sizes, int n_in,
                              void* d_out, int out_size, void* d_ws, size_t ws_size,
                              hipStream_t stream) {
    // inputs: x(0), edge_index(1), num_nodes(2), edge_weight(3), W(4), b(5), alpha(6)
    const float* x      = (const float*)d_in[0];
    const void*  eidx   = d_in[1];
    const float* ew     = (const float*)d_in[3];
    const float* W      = (const float*)d_in[4];
    const float* bias   = (const float*)d_in[5];
    const float* alphaP = (const float*)d_in[6];

    const int NN = in_sizes[0] / DIM;       // < 2^17 required (harness: 100000)
    const int E  = in_sizes[3];
    const int NB = (NN + NPB - 1) / NPB;    // 196 buckets

    // ws layout (~62 MB of 256 MB): aggb u16[NN*DIM] | xb u16[NN*DIM]
    //   | srcw u64[E] | srcw_tmp u64[E] | rowstart int[NN]
    //   | gcnt[256] | gstart[257] | gcursor[256] | flags[2]
    unsigned short* aggb = (unsigned short*)d_ws;
    unsigned short* xb   = aggb + (size_t)NN * DIM;
    unsigned long long* srcw     = (unsigned long long*)(xb + (size_t)NN * DIM);
    unsigned long long* srcw_tmp = srcw + E;
    int* rowstart = (int*)(srcw_tmp + E);
    int* gcnt     = rowstart + NN;
    int* gstart   = gcnt + 256;
    int* gcursor  = gstart + 257;
    int* flags    = gcursor + 256;

    float* out = (float*)d_out;

    init_kernel<<<1, 256, 0, stream>>>(gcnt, (const unsigned int*)eidx, flags);

    int n8 = NN * DIM / 8;
    prep_kernel<<<2048, 256, 0, stream>>>(x, xb, n8, eidx, gcnt, flags, E, NB);

    scanb_kernel<<<1, 256, 0, stream>>>(gcnt, gstart, gcursor, NB, E);

    int a1blocks = (E + A1_EPB - 1) / A1_EPB;   // 313
    part_kernel<<<a1blocks, 256, 0, stream>>>(eidx, ew, gcursor, srcw_tmp, flags, E);

    sort_kernel<<<NB, 512, 0, stream>>>(srcw_tmp, gstart, srcw, rowstart, NN);

    int gblocks = (NN + 15) / 16;               // 16 nodes / 256-thr block
    gather_kernel<<<gblocks, 256, 0, stream>>>(xb, (const uint2*)srcw, rowstart,
                                               aggb, NN, E);

    int fblocks = (NN + FROWS - 1) / FROWS;
    finish_kernel<<<fblocks, 512, 0, stream>>>(aggb, out, xb, W, bias, alphaP, NN);
}

// Round 12
// 102.364 us; speedup vs baseline: 1.3661x; 1.3661x over previous
//
#include <hip/hip_runtime.h>
#include <hip/hip_bf16.h>

#define DIM 128
#define NPB 512                 // nodes per bucket (pow2, shift 9)
#define NPB_SHIFT 9
// NN < 2^17 (=131072) required by the 17-bit src/dst packing; harness uses 100000.

#define A1_EPT 8
#define A1_EPB (256 * A1_EPT)   // 2048 edges per partition block
#define NBLK_STRIDE 512         // bhistT row stride (E <= 512*2048 = 1,048,576)

#define FROWS 64      // finish: M-tile rows per block
#define FPAD 136      // bf16 row stride in LDS: 272B -> 2-way bank alias on b128 (free)

typedef __attribute__((ext_vector_type(8))) short bf16x8;
typedef __attribute__((ext_vector_type(8))) unsigned short u16x8;
typedef __attribute__((ext_vector_type(4))) float f32x4;

__device__ __forceinline__ short f2bf(float f) {
    union { __hip_bfloat16 h; short s; } u;
    u.h = __float2bfloat16(f);   // round-to-nearest-even
    return u.s;
}
__device__ __forceinline__ float bf2f(unsigned short s) {
    union { unsigned int u; float f; } c;
    c.u = ((unsigned int)s) << 16;
    return c.f;
}

__device__ __forceinline__ int load_dst(const void* eidx, int flag64, int E, int e) {
    return flag64 ? (int)((const long long*)eidx)[E + e] : ((const int*)eidx)[E + e];
}
__device__ __forceinline__ int load_src(const void* eidx, int flag64, int E, int e) {
    return flag64 ? (int)((const long long*)eidx)[e] : ((const int*)eidx)[e];
}

// ---------------------------------------------------------------------------
// Prep: cvt x f32 -> xb bf16 (pure stream) + int64/int32 edge-index detect
// (values < 2^17 => int64 high words of first 128 entries all zero).
// No global atomics, nothing to zero.
// ---------------------------------------------------------------------------
__global__ __launch_bounds__(256) void prep_kernel(
        const float* __restrict__ x, unsigned short* __restrict__ xb, int n8,
        const unsigned int* __restrict__ e, int* __restrict__ flags) {
    const int stride = gridDim.x * blockDim.x;
    const int t0 = blockIdx.x * blockDim.x + threadIdx.x;
    for (int t = t0; t < n8; t += stride) {
        const float4* pp = (const float4*)(x + (size_t)t * 8);
        float4 a = pp[0], b = pp[1];
        u16x8 o;
        o[0] = (unsigned short)f2bf(a.x); o[1] = (unsigned short)f2bf(a.y);
        o[2] = (unsigned short)f2bf(a.z); o[3] = (unsigned short)f2bf(a.w);
        o[4] = (unsigned short)f2bf(b.x); o[5] = (unsigned short)f2bf(b.y);
        o[6] = (unsigned short)f2bf(b.z); o[7] = (unsigned short)f2bf(b.w);
        *(u16x8*)(xb + (size_t)t * 8) = o;
    }
    if (blockIdx.x == 0 && threadIdx.x == 0) {
        int ok64 = 1;
        for (int t = 0; t < 128; ++t) {
            if (e[2 * t + 1] != 0u) { ok64 = 0; break; }
        }
        flags[0] = ok64;
    }
}

// ---------------------------------------------------------------------------
// part1: per-block LDS bucket histogram of its 2048 edges, written to the
// block's OWN row slots bhistT[bucket*NBLK_STRIDE + blk]. No contention.
// ---------------------------------------------------------------------------
__global__ __launch_bounds__(256) void part1_kernel(
        const void* __restrict__ eidx, int* __restrict__ bhistT,
        const int* __restrict__ flags, int E) {
    __shared__ int bcnt[256];
    const int tid = threadIdx.x;
    const int blk = blockIdx.x;
    const int base = blk * A1_EPB;
    const int f = flags[0];
    bcnt[tid] = 0;
    __syncthreads();
    #pragma unroll
    for (int i = 0; i < A1_EPT; ++i) {
        int e = base + tid + i * 256;
        if (e < E) atomicAdd(&bcnt[load_dst(eidx, f, E, e) >> NPB_SHIFT], 1);
    }
    __syncthreads();
    bhistT[tid * NBLK_STRIDE + blk] = bcnt[tid];   // uncontended
}

// ---------------------------------------------------------------------------
// scancol: one block per bucket; exclusive scan over the nblk block counts
// (in place) + colsum[bucket]. 512 threads, Hillis-Steele on 512 slots.
// ---------------------------------------------------------------------------
__global__ __launch_bounds__(512) void scancol_kernel(
        int* __restrict__ bhistT, int* __restrict__ colsum, int nblk) {
    __shared__ int s[512];
    const int tid = threadIdx.x;
    const int bu = blockIdx.x;
    int v = (tid < nblk) ? bhistT[bu * NBLK_STRIDE + tid] : 0;
    s[tid] = v;
    __syncthreads();
    for (int off = 1; off < 512; off <<= 1) {
        int t = (tid >= off) ? s[tid - off] : 0;
        __syncthreads();
        s[tid] += t;
        __syncthreads();
    }
    if (tid < nblk) bhistT[bu * NBLK_STRIDE + tid] = s[tid] - v;   // exclusive
    if (tid == 511) colsum[bu] = s[511];
}

// ---------------------------------------------------------------------------
// scanb (1 block): gstart = exclusive scan of colsum; gstart[NB] = E.
// ---------------------------------------------------------------------------
__global__ __launch_bounds__(256) void scanb_kernel(
        const int* __restrict__ colsum, int* __restrict__ gstart, int NB, int E) {
    __shared__ int s[256];
    const int tid = threadIdx.x;
    int val = (tid < NB) ? colsum[tid] : 0;
    s[tid] = val;
    __syncthreads();
    for (int off = 1; off < 256; off <<= 1) {
        int t = (tid >= off) ? s[tid - off] : 0;
        __syncthreads();
        s[tid] += t;
        __syncthreads();
    }
    if (tid < NB) gstart[tid] = s[tid] - val;
    if (tid == NB) gstart[NB] = E;   // NB < 256 guaranteed (NN < 2^17)
}

// ---------------------------------------------------------------------------
// part2: recompute LDS hist + scan + rank (deterministic), stage grouped by
// bucket (pk = w32[57:26] | dst_local[25:17] | src[16:0]), write runs at
// gstart[bu] + bhistT[bu][blk] + rank. ZERO global atomics.
// ---------------------------------------------------------------------------
__global__ __launch_bounds__(256) void part2_kernel(
        const void* __restrict__ eidx, const float* __restrict__ ew,
        const int* __restrict__ bhistT, const int* __restrict__ gstart,
        unsigned long long* __restrict__ srcw_tmp,
        const int* __restrict__ flags, int E) {
    __shared__ unsigned long long stage[A1_EPB];   // 16 KB
    __shared__ unsigned char sbid[A1_EPB];         //  2 KB
    __shared__ int bcnt[256], bscan[256], bcur[256], brun[256];
    const int tid = threadIdx.x;
    const int blk = blockIdx.x;
    const int base = blk * A1_EPB;
    const int f = flags[0];

    bcnt[tid] = 0;
    __syncthreads();

    unsigned long long pk[A1_EPT];
    unsigned char bid[A1_EPT];
    #pragma unroll
    for (int i = 0; i < A1_EPT; ++i) {
        int e = base + tid + i * 256;
        bid[i] = 0xFF;
        if (e < E) {
            int src = load_src(eidx, f, E, e);
            int dst = load_dst(eidx, f, E, e);
            unsigned int w = __float_as_uint(ew[e]);
            int b = dst >> NPB_SHIFT;
            pk[i] = ((unsigned long long)w << 26)
                  | ((unsigned long long)(dst & (NPB - 1)) << 17)
                  | (unsigned long long)(unsigned)src;
            bid[i] = (unsigned char)b;
            atomicAdd(&bcnt[b], 1);
        }
    }
    __syncthreads();

    // exclusive scan of bcnt (Hillis-Steele on 256)
    int val = bcnt[tid];
    bscan[tid] = val;
    __syncthreads();
    for (int off = 1; off < 256; off <<= 1) {
        int t = (tid >= off) ? bscan[tid - off] : 0;
        __syncthreads();
        bscan[tid] += t;
        __syncthreads();
    }
    int excl = bscan[tid] - val;
    __syncthreads();
    bscan[tid] = excl;        // now exclusive
    bcur[tid] = excl;
    // deterministic global run offset for this (block, bucket)
    brun[tid] = gstart[tid] + bhistT[tid * NBLK_STRIDE + blk];
    __syncthreads();

    // rank + stage (bucket-grouped)
    #pragma unroll
    for (int i = 0; i < A1_EPT; ++i) {
        if (bid[i] != 0xFF) {
            int slot = atomicAdd(&bcur[bid[i]], 1);
            stage[slot] = pk[i];
            sbid[slot] = bid[i];
        }
    }
    __syncthreads();

    int tot = (base + A1_EPB <= E) ? A1_EPB : (E - base);
    for (int s = tid; s < tot; s += 256) {
        int b = sbid[s];
        srcw_tmp[brun[b] + (s - bscan[b])] = stage[s];
    }
}

// ---------------------------------------------------------------------------
// A2 bucket-local sort (512 threads/block, 1 block/bucket): count per node
// (LDS), 512-wide scan, write node rowstart (coalesced), place final
// (w<<32|src) payloads. All payload writes land in the bucket's contiguous
// slot region from ONE block -> lines fill in L2 -> ~1x write amp.
// ---------------------------------------------------------------------------
__global__ __launch_bounds__(512) void sort_kernel(
        const unsigned long long* __restrict__ srcw_tmp,
        const int* __restrict__ gstart, unsigned long long* __restrict__ srcw,
        int* __restrict__ rowstart, int nn) {
    __shared__ int cnt[NPB], cur[NPB], s[NPB];
    const int tid = threadIdx.x;
    const int b = blockIdx.x;
    const int node0 = b << NPB_SHIFT;
    const int e0 = gstart[b], e1 = gstart[b + 1];

    cnt[tid] = 0;
    __syncthreads();
    for (int e = e0 + tid; e < e1; e += 512)
        atomicAdd(&cnt[(int)((srcw_tmp[e] >> 17) & (NPB - 1))], 1);
    __syncthreads();

    // exclusive scan over 512 (Hillis-Steele)
    int val = cnt[tid];
    s[tid] = val;
    __syncthreads();
    for (int off = 1; off < 512; off <<= 1) {
        int t = (tid >= off) ? s[tid - off] : 0;
        __syncthreads();
        s[tid] += t;
        __syncthreads();
    }
    int excl = s[tid] - val;
    cur[tid] = excl;
    __syncthreads();

    // node-level rowstart (coalesced, one per thread)
    int nbn = nn - node0; if (nbn > NPB) nbn = NPB;
    if (tid < nbn) rowstart[node0 + tid] = e0 + excl;

    // place payloads
    for (int e = e0 + tid; e < e1; e += 512) {
        unsigned long long pk = srcw_tmp[e];
        int dl = (int)((pk >> 17) & (NPB - 1));
        int pos = e0 + atomicAdd(&cur[dl], 1);
        srcw[pos] = ((pk >> 26) << 32) | (pk & 0x1FFFFULL);
    }
}

// ---------------------------------------------------------------------------
// Gather: 4 nodes per wave (16 lanes per node, lane owns 8 dims = 16B bf16).
// Unified contiguous segment per node; 4-edge unroll -> up to 16 row-fetches
// in flight per wave. No atomics.
// ---------------------------------------------------------------------------
__global__ __launch_bounds__(256) void gather_kernel(
        const unsigned short* __restrict__ xb, const uint2* __restrict__ srcw,
        const int* __restrict__ rowstart, unsigned short* __restrict__ aggb,
        int nn, int E) {
    int g = (blockIdx.x * blockDim.x + threadIdx.x) >> 4;   // node
    int sub16 = threadIdx.x & 15;                           // owns dims [8*sub16, +8)
    if (g >= nn) return;
    int n0 = rowstart[g];
    int n1 = (g + 1 < nn) ? rowstart[g + 1] : E;
    float acc[8] = {0.f, 0.f, 0.f, 0.f, 0.f, 0.f, 0.f, 0.f};
    int e = n0;
    for (; e + 4 <= n1; e += 4) {
        uint2 sw0 = srcw[e];
        uint2 sw1 = srcw[e + 1];
        uint2 sw2 = srcw[e + 2];
        uint2 sw3 = srcw[e + 3];
        u16x8 x0 = *(const u16x8*)(xb + (size_t)sw0.x * DIM + sub16 * 8);
        u16x8 x1 = *(const u16x8*)(xb + (size_t)sw1.x * DIM + sub16 * 8);
        u16x8 x2 = *(const u16x8*)(xb + (size_t)sw2.x * DIM + sub16 * 8);
        u16x8 x3 = *(const u16x8*)(xb + (size_t)sw3.x * DIM + sub16 * 8);
        float w0 = __uint_as_float(sw0.y);
        float w1 = __uint_as_float(sw1.y);
        float w2 = __uint_as_float(sw2.y);
        float w3 = __uint_as_float(sw3.y);
        #pragma unroll
        for (int j = 0; j < 8; ++j) {
            acc[j] = fmaf(bf2f(x0[j]), w0, acc[j]);
            acc[j] = fmaf(bf2f(x1[j]), w1, acc[j]);
            acc[j] = fmaf(bf2f(x2[j]), w2, acc[j]);
            acc[j] = fmaf(bf2f(x3[j]), w3, acc[j]);
        }
    }
    for (; e < n1; ++e) {
        uint2 sw = srcw[e];
        u16x8 xr = *(const u16x8*)(xb + (size_t)sw.x * DIM + sub16 * 8);
        float w = __uint_as_float(sw.y);
        #pragma unroll
        for (int j = 0; j < 8; ++j) acc[j] = fmaf(bf2f(xr[j]), w, acc[j]);
    }
    float inv = 1.0f / fmaxf((float)(n1 - n0), 1.0f);
    u16x8 o;
    #pragma unroll
    for (int j = 0; j < 8; ++j) o[j] = (unsigned short)f2bf(acc[j] * inv);
    *(u16x8*)(aggb + (size_t)g * DIM + sub16 * 8) = o;
}

// ---------------------------------------------------------------------------
// MFMA finish: out = xb + alpha*(aggb @ W^T + b). aggb, xb bf16 in ws; out
// f32 in d_out. 512 threads = 8 waves; 64-row M-tile; wave w owns output
// cols [16w,16w+16). C/D map: col=lane&15, row=(lane>>4)*4+reg  [verified,
// learn_hip m89/m91]. Residual from bf16 xb: +<=0.016 abs err, OK.
// ---------------------------------------------------------------------------
__global__ __launch_bounds__(512) void finish_kernel(
        const unsigned short* __restrict__ aggb, float* __restrict__ out,
        const unsigned short* __restrict__ xb, const float* __restrict__ W,
        const float* __restrict__ bias, const float* __restrict__ alphaP, int nn) {
    __shared__ alignas(16) unsigned short A_lds[FROWS * FPAD];   // 17408 B
    const int tid  = threadIdx.x;
    const int wv   = tid >> 6;          // wave 0..7
    const int lane = tid & 63;
    const int half = lane >> 4;         // 0..3 (K-group / row-group)
    const int l16  = lane & 15;         // M-row for A, N-col for B and C/D
    const int b0   = blockIdx.x * FROWS;
    const float alpha = alphaP[0];

    // ---- B-frags: W[jcol][kt*32 + half*8 .. +8] as bf16, loaded once ----
    const int jcol = wv * 16 + l16;
    bf16x8 bfrag[4];
    #pragma unroll
    for (int kt = 0; kt < 4; ++kt) {
        const float4* w4 = (const float4*)(W + (size_t)jcol * DIM + kt * 32 + half * 8);
        float4 lo = w4[0], hi = w4[1];
        bf16x8 b;
        b[0] = f2bf(lo.x); b[1] = f2bf(lo.y); b[2] = f2bf(lo.z); b[3] = f2bf(lo.w);
        b[4] = f2bf(hi.x); b[5] = f2bf(hi.y); b[6] = f2bf(hi.z); b[7] = f2bf(hi.w);
        bfrag[kt] = b;
    }
    const float bias_j = bias[jcol];

    // ---- stage 64 bf16 agg rows -> LDS: 1024 chunks of 16B, 2 iters ----
    #pragma unroll
    for (int it = 0; it < 2; ++it) {
        int p = it * 512 + tid;          // 0..1023
        int row = p >> 4;                // 0..63
        int c8 = p & 15;                 // 16B chunk within row
        int node = b0 + row;
        u16x8 v = {0, 0, 0, 0, 0, 0, 0, 0};
        if (node < nn) v = *(const u16x8*)(aggb + (size_t)node * DIM + c8 * 8);
        *(u16x8*)&A_lds[row * FPAD + c8 * 8] = v;
    }
    __syncthreads();

    // ---- 4 sub-tiles of 16 rows: MFMA + fused epilogue ----
    #pragma unroll
    for (int mt = 0; mt < 4; ++mt) {
        f32x4 acc = {0.f, 0.f, 0.f, 0.f};
        #pragma unroll
        for (int kt = 0; kt < 4; ++kt) {
            const bf16x8 a = *(const bf16x8*)&A_lds[(mt * 16 + l16) * FPAD + kt * 32 + half * 8];
            acc = __builtin_amdgcn_mfma_f32_16x16x32_bf16(a, bfrag[kt], acc, 0, 0, 0);
        }
        #pragma unroll
        for (int r = 0; r < 4; ++r) {
            int grow = b0 + mt * 16 + half * 4 + r;
            if (grow < nn) {
                size_t idx = (size_t)grow * DIM + jcol;
                out[idx] = bf2f(xb[idx]) + alpha * (acc[r] + bias_j);
            }
        }
    }
}

extern "C" void kernel_launch(void* const* d_in, const int* in_sizes, int n_in,
                              void* d_out, int out_size, void* d_ws, size_t ws_size,
                              hipStream_t stream) {
    // inputs: x(0), edge_index(1), num_nodes(2), edge_weight(3), W(4), b(5), alpha(6)
    const float* x      = (const float*)d_in[0];
    const void*  eidx   = d_in[1];
    const float* ew     = (const float*)d_in[3];
    const float* W      = (const float*)d_in[4];
    const float* bias   = (const float*)d_in[5];
    const float* alphaP = (const float*)d_in[6];

    const int NN = in_sizes[0] / DIM;       // < 2^17 required (harness: 100000)
    const int E  = in_sizes[3];
    const int NB = (NN + NPB - 1) / NPB;    // 196 buckets
    const int nblk = (E + A1_EPB - 1) / A1_EPB;   // 313 partition blocks (<= 512)

    // ws layout (~63 MB of 256 MB): aggb u16[NN*DIM] | xb u16[NN*DIM]
    //   | srcw u64[E] | srcw_tmp u64[E] | rowstart int[NN]
    //   | bhistT int[256*NBLK_STRIDE] | colsum[256] | gstart[257] | flags[2]
    unsigned short* aggb = (unsigned short*)d_ws;
    unsigned short* xb   = aggb + (size_t)NN * DIM;
    unsigned long long* srcw     = (unsigned long long*)(xb + (size_t)NN * DIM);
    unsigned long long* srcw_tmp = srcw + E;
    int* rowstart = (int*)(srcw_tmp + E);
    int* bhistT   = rowstart + NN;
    int* colsum   = bhistT + 256 * NBLK_STRIDE;
    int* gstart   = colsum + 256;
    int* flags    = gstart + 257;

    float* out = (float*)d_out;

    int n8 = NN * DIM / 8;
    prep_kernel<<<2048, 256, 0, stream>>>(x, xb, n8, (const unsigned int*)eidx, flags);

    part1_kernel<<<nblk, 256, 0, stream>>>(eidx, bhistT, flags, E);

    scancol_kernel<<<NB, 512, 0, stream>>>(bhistT, colsum, nblk);

    scanb_kernel<<<1, 256, 0, stream>>>(colsum, gstart, NB, E);

    part2_kernel<<<nblk, 256, 0, stream>>>(eidx, ew, bhistT, gstart, srcw_tmp, flags, E);

    sort_kernel<<<NB, 512, 0, stream>>>(srcw_tmp, gstart, srcw, rowstart, NN);

    int gblocks = (NN + 15) / 16;               // 16 nodes / 256-thr block
    gather_kernel<<<gblocks, 256, 0, stream>>>(xb, (const uint2*)srcw, rowstart,
                                               aggb, NN, E);

    int fblocks = (NN + FROWS - 1) / FROWS;
    finish_kernel<<<fblocks, 512, 0, stream>>>(aggb, out, xb, W, bias, alphaP, NN);
}

// Round 13
// 101.744 us; speedup vs baseline: 1.3744x; 1.0061x over previous
//
#include <hip/hip_runtime.h>
#include <hip/hip_bf16.h>

#define DIM 128
#define NPB 512                 // nodes per bucket (pow2, shift 9)
#define NPB_SHIFT 9
// NN < 2^17 (=131072) required by the 17-bit src/dst packing; harness uses 100000.

#define A1_EPT 8
#define A1_EPB (256 * A1_EPT)   // 2048 edges per partition block
#define NBLK_STRIDE 512         // bhistT row stride (E <= 512*2048 = 1,048,576)

#define FROWS 64      // finish: M-tile rows per block
#define FPAD 136      // bf16 row stride in LDS: 272B -> 2-way bank alias on b128 (free)

typedef __attribute__((ext_vector_type(8))) short bf16x8;
typedef __attribute__((ext_vector_type(8))) unsigned short u16x8;
typedef __attribute__((ext_vector_type(4))) float f32x4;

__device__ __forceinline__ short f2bf(float f) {
    union { __hip_bfloat16 h; short s; } u;
    u.h = __float2bfloat16(f);   // round-to-nearest-even
    return u.s;
}
__device__ __forceinline__ float bf2f(unsigned short s) {
    union { unsigned int u; float f; } c;
    c.u = ((unsigned int)s) << 16;
    return c.f;
}

__device__ __forceinline__ int load_dst(const void* eidx, int flag64, int E, int e) {
    return flag64 ? (int)((const long long*)eidx)[E + e] : ((const int*)eidx)[E + e];
}
__device__ __forceinline__ int load_src(const void* eidx, int flag64, int E, int e) {
    return flag64 ? (int)((const long long*)eidx)[e] : ((const int*)eidx)[e];
}

// Per-block int64/int32 self-detect (values < 2^17 => int64 high words of the
// first 128 entries are all zero; int32 data there is random node indices).
// tid 0 computes, LDS-broadcast. Deterministic, identical in every block.
__device__ __forceinline__ int detect64_block(const unsigned int* e, int* sdet) {
    if (threadIdx.x == 0) {
        int ok64 = 1;
        for (int t = 0; t < 128; ++t) {
            if (e[2 * t + 1] != 0u) { ok64 = 0; break; }
        }
        *sdet = ok64;
    }
    __syncthreads();
    return *sdet;
}

// ---------------------------------------------------------------------------
// Prep (fused): cvt x f32 -> xb bf16 (pure stream, all blocks) + part1 bucket
// histogram (blocks < nblk: LDS hist of own 2048-edge chunk -> own bhistT row,
// uncontended).
// ---------------------------------------------------------------------------
__global__ __launch_bounds__(256) void prep_kernel(
        const float* __restrict__ x, unsigned short* __restrict__ xb, int n8,
        const void* __restrict__ eidx, int* __restrict__ bhistT, int E, int nblk) {
    __shared__ int bcnt[256];
    __shared__ int sdet;
    const int tid = threadIdx.x;
    const int blk = blockIdx.x;
    const bool hist = (blk < nblk);

    int f = 0;
    if (hist) {
        f = detect64_block((const unsigned int*)eidx, &sdet);
        bcnt[tid] = 0;
        __syncthreads();
        const int base = blk * A1_EPB;
        #pragma unroll
        for (int i = 0; i < A1_EPT; ++i) {
            int e = base + tid + i * 256;
            if (e < E) atomicAdd(&bcnt[load_dst(eidx, f, E, e) >> NPB_SHIFT], 1);
        }
    }

    const int stride = gridDim.x * blockDim.x;
    for (int t = blk * blockDim.x + tid; t < n8; t += stride) {
        const float4* pp = (const float4*)(x + (size_t)t * 8);
        float4 a = pp[0], b = pp[1];
        u16x8 o;
        o[0] = (unsigned short)f2bf(a.x); o[1] = (unsigned short)f2bf(a.y);
        o[2] = (unsigned short)f2bf(a.z); o[3] = (unsigned short)f2bf(a.w);
        o[4] = (unsigned short)f2bf(b.x); o[5] = (unsigned short)f2bf(b.y);
        o[6] = (unsigned short)f2bf(b.z); o[7] = (unsigned short)f2bf(b.w);
        *(u16x8*)(xb + (size_t)t * 8) = o;
    }

    if (hist) {
        __syncthreads();
        bhistT[tid * NBLK_STRIDE + blk] = bcnt[tid];   // uncontended own slot
    }
}

// ---------------------------------------------------------------------------
// scancol: one block per bucket; exclusive scan over the nblk block counts
// (in place) + colsum[bucket]. 512 threads, Hillis-Steele on 512 slots.
// ---------------------------------------------------------------------------
__global__ __launch_bounds__(512) void scancol_kernel(
        int* __restrict__ bhistT, int* __restrict__ colsum, int nblk) {
    __shared__ int s[512];
    const int tid = threadIdx.x;
    const int bu = blockIdx.x;
    int v = (tid < nblk) ? bhistT[bu * NBLK_STRIDE + tid] : 0;
    s[tid] = v;
    __syncthreads();
    for (int off = 1; off < 512; off <<= 1) {
        int t = (tid >= off) ? s[tid - off] : 0;
        __syncthreads();
        s[tid] += t;
        __syncthreads();
    }
    if (tid < nblk) bhistT[bu * NBLK_STRIDE + tid] = s[tid] - v;   // exclusive
    if (tid == 511) colsum[bu] = s[511];
}

// ---------------------------------------------------------------------------
// scanb (1 block): gstart = exclusive scan of colsum; gstart[NB] = E.
// ---------------------------------------------------------------------------
__global__ __launch_bounds__(256) void scanb_kernel(
        const int* __restrict__ colsum, int* __restrict__ gstart, int NB, int E) {
    __shared__ int s[256];
    const int tid = threadIdx.x;
    int val = (tid < NB) ? colsum[tid] : 0;
    s[tid] = val;
    __syncthreads();
    for (int off = 1; off < 256; off <<= 1) {
        int t = (tid >= off) ? s[tid - off] : 0;
        __syncthreads();
        s[tid] += t;
        __syncthreads();
    }
    if (tid < NB) gstart[tid] = s[tid] - val;
    if (tid == NB) gstart[NB] = E;   // NB < 256 guaranteed (NN < 2^17)
}

// ---------------------------------------------------------------------------
// part2: recompute LDS hist + scan + rank (deterministic), stage grouped by
// bucket (pk = w32[57:26] | dst_local[25:17] | src[16:0]), write runs at
// gstart[bu] + bhistT[bu][blk] + rank. ZERO global atomics.
// ---------------------------------------------------------------------------
__global__ __launch_bounds__(256) void part2_kernel(
        const void* __restrict__ eidx, const float* __restrict__ ew,
        const int* __restrict__ bhistT, const int* __restrict__ gstart,
        unsigned long long* __restrict__ srcw_tmp, int E) {
    __shared__ unsigned long long stage[A1_EPB];   // 16 KB
    __shared__ unsigned char sbid[A1_EPB];         //  2 KB
    __shared__ int bcnt[256], bscan[256], bcur[256], brun[256];
    __shared__ int sdet;
    const int tid = threadIdx.x;
    const int blk = blockIdx.x;
    const int base = blk * A1_EPB;
    const int f = detect64_block((const unsigned int*)eidx, &sdet);

    bcnt[tid] = 0;
    __syncthreads();

    unsigned long long pk[A1_EPT];
    unsigned char bid[A1_EPT];
    #pragma unroll
    for (int i = 0; i < A1_EPT; ++i) {
        int e = base + tid + i * 256;
        bid[i] = 0xFF;
        if (e < E) {
            int src = load_src(eidx, f, E, e);
            int dst = load_dst(eidx, f, E, e);
            unsigned int w = __float_as_uint(ew[e]);
            int b = dst >> NPB_SHIFT;
            pk[i] = ((unsigned long long)w << 26)
                  | ((unsigned long long)(dst & (NPB - 1)) << 17)
                  | (unsigned long long)(unsigned)src;
            bid[i] = (unsigned char)b;
            atomicAdd(&bcnt[b], 1);
        }
    }
    __syncthreads();

    // exclusive scan of bcnt (Hillis-Steele on 256)
    int val = bcnt[tid];
    bscan[tid] = val;
    __syncthreads();
    for (int off = 1; off < 256; off <<= 1) {
        int t = (tid >= off) ? bscan[tid - off] : 0;
        __syncthreads();
        bscan[tid] += t;
        __syncthreads();
    }
    int excl = bscan[tid] - val;
    __syncthreads();
    bscan[tid] = excl;        // now exclusive
    bcur[tid] = excl;
    // deterministic global run offset for this (block, bucket)
    brun[tid] = gstart[tid] + bhistT[tid * NBLK_STRIDE + blk];
    __syncthreads();

    // rank + stage (bucket-grouped)
    #pragma unroll
    for (int i = 0; i < A1_EPT; ++i) {
        if (bid[i] != 0xFF) {
            int slot = atomicAdd(&bcur[bid[i]], 1);
            stage[slot] = pk[i];
            sbid[slot] = bid[i];
        }
    }
    __syncthreads();

    int tot = (base + A1_EPB <= E) ? A1_EPB : (E - base);
    for (int s = tid; s < tot; s += 256) {
        int b = sbid[s];
        srcw_tmp[brun[b] + (s - bscan[b])] = stage[s];
    }
}

// ---------------------------------------------------------------------------
// A2 bucket-local sort (512 threads/block, 1 block/bucket): count per node
// (LDS), 512-wide scan, write node rowstart (coalesced), place final
// (w<<32|src) payloads. All payload writes land in the bucket's contiguous
// slot region from ONE block -> lines fill in L2 -> ~1x write amp.
// ---------------------------------------------------------------------------
__global__ __launch_bounds__(512) void sort_kernel(
        const unsigned long long* __restrict__ srcw_tmp,
        const int* __restrict__ gstart, unsigned long long* __restrict__ srcw,
        int* __restrict__ rowstart, int nn) {
    __shared__ int cnt[NPB], cur[NPB], s[NPB];
    const int tid = threadIdx.x;
    const int b = blockIdx.x;
    const int node0 = b << NPB_SHIFT;
    const int e0 = gstart[b], e1 = gstart[b + 1];

    cnt[tid] = 0;
    __syncthreads();
    for (int e = e0 + tid; e < e1; e += 512)
        atomicAdd(&cnt[(int)((srcw_tmp[e] >> 17) & (NPB - 1))], 1);
    __syncthreads();

    // exclusive scan over 512 (Hillis-Steele)
    int val = cnt[tid];
    s[tid] = val;
    __syncthreads();
    for (int off = 1; off < 512; off <<= 1) {
        int t = (tid >= off) ? s[tid - off] : 0;
        __syncthreads();
        s[tid] += t;
        __syncthreads();
    }
    int excl = s[tid] - val;
    cur[tid] = excl;
    __syncthreads();

    // node-level rowstart (coalesced, one per thread)
    int nbn = nn - node0; if (nbn > NPB) nbn = NPB;
    if (tid < nbn) rowstart[node0 + tid] = e0 + excl;

    // place payloads
    for (int e = e0 + tid; e < e1; e += 512) {
        unsigned long long pk = srcw_tmp[e];
        int dl = (int)((pk >> 17) & (NPB - 1));
        int pos = e0 + atomicAdd(&cur[dl], 1);
        srcw[pos] = ((pk >> 26) << 32) | (pk & 0x1FFFFULL);
    }
}

// ---------------------------------------------------------------------------
// Gather: 4 nodes per wave (16 lanes per node, lane owns 8 dims = 16B bf16).
// Batched 8-edge body with zero-weight padding: every node issues ALL (<=8)
// row-fetches in one dependent round (pads read row 0, L2-hot, w=0). No
// serial remainder, no atomics.
// ---------------------------------------------------------------------------
__global__ __launch_bounds__(256) void gather_kernel(
        const unsigned short* __restrict__ xb, const uint2* __restrict__ srcw,
        const int* __restrict__ rowstart, unsigned short* __restrict__ aggb,
        int nn, int E) {
    int g = (blockIdx.x * blockDim.x + threadIdx.x) >> 4;   // node
    int sub16 = threadIdx.x & 15;                           // owns dims [8*sub16, +8)
    if (g >= nn) return;
    int n0 = rowstart[g];
    int n1 = (g + 1 < nn) ? rowstart[g + 1] : E;
    float acc[8] = {0.f, 0.f, 0.f, 0.f, 0.f, 0.f, 0.f, 0.f};
    for (int e = n0; e < n1; e += 8) {
        int rem = n1 - e;
        uint2 sws[8];
        #pragma unroll
        for (int i = 0; i < 8; ++i) {
            if (i < rem) sws[i] = srcw[e + i];
            else { sws[i].x = 0u; sws[i].y = 0u; }   // w=0: contributes nothing
        }
        u16x8 xs[8];
        #pragma unroll
        for (int i = 0; i < 8; ++i)
            xs[i] = *(const u16x8*)(xb + (size_t)sws[i].x * DIM + sub16 * 8);
        #pragma unroll
        for (int i = 0; i < 8; ++i) {
            float w = __uint_as_float(sws[i].y);
            #pragma unroll
            for (int j = 0; j < 8; ++j)
                acc[j] = fmaf(bf2f(xs[i][j]), w, acc[j]);
        }
    }
    float inv = 1.0f / fmaxf((float)(n1 - n0), 1.0f);
    u16x8 o;
    #pragma unroll
    for (int j = 0; j < 8; ++j) o[j] = (unsigned short)f2bf(acc[j] * inv);
    *(u16x8*)(aggb + (size_t)g * DIM + sub16 * 8) = o;
}

// ---------------------------------------------------------------------------
// MFMA finish: out = xb + alpha*(aggb @ W^T + b). aggb, xb bf16 in ws; out
// f32 in d_out. 512 threads = 8 waves; 64-row M-tile; wave w owns output
// cols [16w,16w+16). C/D map: col=lane&15, row=(lane>>4)*4+reg  [verified,
// learn_hip m89/m91]. Residual from bf16 xb: +<=0.016 abs err, OK.
// ---------------------------------------------------------------------------
__global__ __launch_bounds__(512) void finish_kernel(
        const unsigned short* __restrict__ aggb, float* __restrict__ out,
        const unsigned short* __restrict__ xb, const float* __restrict__ W,
        const float* __restrict__ bias, const float* __restrict__ alphaP, int nn) {
    __shared__ alignas(16) unsigned short A_lds[FROWS * FPAD];   // 17408 B
    const int tid  = threadIdx.x;
    const int wv   = tid >> 6;          // wave 0..7
    const int lane = tid & 63;
    const int half = lane >> 4;         // 0..3 (K-group / row-group)
    const int l16  = lane & 15;         // M-row for A, N-col for B and C/D
    const int b0   = blockIdx.x * FROWS;
    const float alpha = alphaP[0];

    // ---- B-frags: W[jcol][kt*32 + half*8 .. +8] as bf16, loaded once ----
    const int jcol = wv * 16 + l16;
    bf16x8 bfrag[4];
    #pragma unroll
    for (int kt = 0; kt < 4; ++kt) {
        const float4* w4 = (const float4*)(W + (size_t)jcol * DIM + kt * 32 + half * 8);
        float4 lo = w4[0], hi = w4[1];
        bf16x8 b;
        b[0] = f2bf(lo.x); b[1] = f2bf(lo.y); b[2] = f2bf(lo.z); b[3] = f2bf(lo.w);
        b[4] = f2bf(hi.x); b[5] = f2bf(hi.y); b[6] = f2bf(hi.z); b[7] = f2bf(hi.w);
        bfrag[kt] = b;
    }
    const float bias_j = bias[jcol];

    // ---- stage 64 bf16 agg rows -> LDS: 1024 chunks of 16B, 2 iters ----
    #pragma unroll
    for (int it = 0; it < 2; ++it) {
        int p = it * 512 + tid;          // 0..1023
        int row = p >> 4;                // 0..63
        int c8 = p & 15;                 // 16B chunk within row
        int node = b0 + row;
        u16x8 v = {0, 0, 0, 0, 0, 0, 0, 0};
        if (node < nn) v = *(const u16x8*)(aggb + (size_t)node * DIM + c8 * 8);
        *(u16x8*)&A_lds[row * FPAD + c8 * 8] = v;
    }
    __syncthreads();

    // ---- 4 sub-tiles of 16 rows: MFMA + fused epilogue ----
    #pragma unroll
    for (int mt = 0; mt < 4; ++mt) {
        f32x4 acc = {0.f, 0.f, 0.f, 0.f};
        #pragma unroll
        for (int kt = 0; kt < 4; ++kt) {
            const bf16x8 a = *(const bf16x8*)&A_lds[(mt * 16 + l16) * FPAD + kt * 32 + half * 8];
            acc = __builtin_amdgcn_mfma_f32_16x16x32_bf16(a, bfrag[kt], acc, 0, 0, 0);
        }
        #pragma unroll
        for (int r = 0; r < 4; ++r) {
            int grow = b0 + mt * 16 + half * 4 + r;
            if (grow < nn) {
                size_t idx = (size_t)grow * DIM + jcol;
                out[idx] = bf2f(xb[idx]) + alpha * (acc[r] + bias_j);
            }
        }
    }
}

extern "C" void kernel_launch(void* const* d_in, const int* in_sizes, int n_in,
                              void* d_out, int out_size, void* d_ws, size_t ws_size,
                              hipStream_t stream) {
    // inputs: x(0), edge_index(1), num_nodes(2), edge_weight(3), W(4), b(5), alpha(6)
    const float* x      = (const float*)d_in[0];
    const void*  eidx   = d_in[1];
    const float* ew     = (const float*)d_in[3];
    const float* W      = (const float*)d_in[4];
    const float* bias   = (const float*)d_in[5];
    const float* alphaP = (const float*)d_in[6];

    const int NN = in_sizes[0] / DIM;       // < 2^17 required (harness: 100000)
    const int E  = in_sizes[3];
    const int NB = (NN + NPB - 1) / NPB;    // 196 buckets
    const int nblk = (E + A1_EPB - 1) / A1_EPB;   // 313 partition blocks (<= 512)

    // ws layout (~63 MB of 256 MB): aggb u16[NN*DIM] | xb u16[NN*DIM]
    //   | srcw u64[E] | srcw_tmp u64[E] | rowstart int[NN]
    //   | bhistT int[256*NBLK_STRIDE] | colsum[256] | gstart[257]
    unsigned short* aggb = (unsigned short*)d_ws;
    unsigned short* xb   = aggb + (size_t)NN * DIM;
    unsigned long long* srcw     = (unsigned long long*)(xb + (size_t)NN * DIM);
    unsigned long long* srcw_tmp = srcw + E;
    int* rowstart = (int*)(srcw_tmp + E);
    int* bhistT   = rowstart + NN;
    int* colsum   = bhistT + 256 * NBLK_STRIDE;
    int* gstart   = colsum + 256;

    float* out = (float*)d_out;

    int n8 = NN * DIM / 8;
    prep_kernel<<<2048, 256, 0, stream>>>(x, xb, n8, eidx, bhistT, E, nblk);

    scancol_kernel<<<NB, 512, 0, stream>>>(bhistT, colsum, nblk);

    scanb_kernel<<<1, 256, 0, stream>>>(colsum, gstart, NB, E);

    part2_kernel<<<nblk, 256, 0, stream>>>(eidx, ew, bhistT, gstart, srcw_tmp, E);

    sort_kernel<<<NB, 512, 0, stream>>>(srcw_tmp, gstart, srcw, rowstart, NN);

    int gblocks = (NN + 15) / 16;               // 16 nodes / 256-thr block
    gather_kernel<<<gblocks, 256, 0, stream>>>(xb, (const uint2*)srcw, rowstart,
                                               aggb, NN, E);

    int fblocks = (NN + FROWS - 1) / FROWS;
    finish_kernel<<<fblocks, 512, 0, stream>>>(aggb, out, xb, W, bias, alphaP, NN);
}